// Round 17
// baseline (177.234 us; speedup 1.0000x reference)
//
#include <hip/hip_runtime.h>
#include <hip/hip_bf16.h>

#define MODEL_DIM 256
#define HIST 8
#define HID 512
#define NNEUR 64
#define IN_DIM 2304   // MODEL_DIM * (1 + HIST)
#define BATCH 32

typedef float v4f __attribute__((ext_vector_type(4)));

__device__ __forceinline__ float geluf(float x) {
    return 0.5f * x * (1.0f + erff(x * 0.70710678118654752440f));
}
__device__ __forceinline__ float f4c(const float4& v, int j) {
    switch (j) { case 0: return v.x; case 1: return v.y; case 2: return v.z; default: return v.w; }
}
__device__ __forceinline__ float4 ntload4(const float* p) {
    v4f v = __builtin_nontemporal_load((const v4f*)p);
    return make_float4(v.x, v.y, v.z, v.w);
}

// ---------------------------------------------------------------------------
// K1h: history GEMV at 32 waves/CU + build_x merged (r16, unchanged).
// grid 2080, block 256. ph[16][64][512] f32
// ---------------------------------------------------------------------------
__global__ __launch_bounds__(256, 8) void k_hist(
        const float* __restrict__ pre, const float* __restrict__ W1,
        const float* __restrict__ emb, const float* __restrict__ Wp,
        const float* __restrict__ bp, float* __restrict__ proj,
        float* __restrict__ ph) {
    const int bid = blockIdx.x;
    const int t   = threadIdx.x;

    if (bid >= 2048) {
        const int b = bid - 2048;
        __shared__ float e[MODEL_DIM];
        e[t] = emb[b * MODEL_DIM + t];
        __syncthreads();
        float acc = bp[t];
        #pragma unroll 4
        for (int k = 0; k < MODEL_DIM; ++k)
            acc = fmaf(e[k], Wp[(size_t)k * MODEL_DIM + t], acc);
        proj[b * MODEL_DIM + t] = acc;
        return;
    }

    const int n  = bid >> 5;
    const int ks = (bid >> 1) & 15;
    const int ch = bid & 1;
    const int w  = t >> 6;
    const int l  = t & 63;
    const int k0 = ks * 128;
    const int cb = ch * 256;

    __shared__ float ps[128];
    __shared__ float red[4][256];
    if (t < 128) ps[t] = pre[k0 + t];
    __syncthreads();

    const float* W = W1 + (size_t)n * IN_DIM * HID
                        + (size_t)(MODEL_DIM + k0 + w * 32) * HID + cb + l * 4;
    const float* pw = ps + w * 32;

    float4 a = make_float4(0.f, 0.f, 0.f, 0.f);
    #pragma unroll 8
    for (int kk = 0; kk < 32; ++kk) {
        float4 wv = ntload4(W + (size_t)kk * HID);
        float s = pw[kk];
        a.x = fmaf(s, wv.x, a.x);
        a.y = fmaf(s, wv.y, a.y);
        a.z = fmaf(s, wv.z, a.z);
        a.w = fmaf(s, wv.w, a.w);
    }
    *((float4*)&red[w][l * 4]) = a;
    __syncthreads();

    if (t < 64) {
        const int c = t * 4;
        float4 r0 = *((const float4*)&red[0][c]);
        float4 r1 = *((const float4*)&red[1][c]);
        float4 r2 = *((const float4*)&red[2][c]);
        float4 r3 = *((const float4*)&red[3][c]);
        float4 o = make_float4(r0.x + r1.x + r2.x + r3.x,
                               r0.y + r1.y + r2.y + r3.y,
                               r0.z + r1.z + r2.z + r3.z,
                               r0.w + r1.w + r2.w + r3.w);
        *((float4*)(ph + ((size_t)ks * NNEUR + n) * HID + cb + c)) = o;
    }
}

// ---------------------------------------------------------------------------
// K1p: proj GEMM + phs pre-reduction (r16, unchanged).
// grid 512 = n(64) x ct(2) x ks(4: K=64). block 256. pp[4][64][32][512] f32
// ---------------------------------------------------------------------------
__global__ __launch_bounds__(256, 4) void k_proj(
        const float* __restrict__ proj, const float* __restrict__ W1,
        const float* __restrict__ ph, float* __restrict__ phs,
        float* __restrict__ pp) {
    const int bid = blockIdx.x;
    const int t  = threadIdx.x;

    if (bid < 64) {
        const size_t slh = (size_t)NNEUR * HID;
        #pragma unroll
        for (int q = 0; q < 2; ++q) {
            const int c = t + q * 256;
            const float* h = ph + (size_t)bid * HID + c;
            float s = 0.0f;
            #pragma unroll
            for (int s5 = 0; s5 < 16; ++s5)
                s += h[(size_t)s5 * slh];
            phs[(size_t)bid * HID + c] = s;
        }
    }

    const int n  = bid >> 3;
    const int ct = (bid >> 2) & 1;
    const int ks = bid & 3;
    const int cg = t & 63;
    const int rg = t >> 6;
    const int col0 = ct * 256 + cg * 4;
    const int row0 = rg * 8;
    const int k0 = ks * 64;

    __shared__ float xs[BATCH][64];
    #pragma unroll
    for (int q = 0; q < 2; ++q) {                 // 32*16 float4 = 512
        int fi  = t + 256 * q;
        int row = fi >> 4;
        int c4v = fi & 15;
        *((float4*)&xs[row][c4v * 4]) =
            *((const float4*)(proj + (size_t)row * MODEL_DIM + k0 + c4v * 4));
    }
    __syncthreads();

    const float* W = W1 + (size_t)n * IN_DIM * HID + (size_t)k0 * HID + col0;

    float acc[8][4];
    #pragma unroll
    for (int i = 0; i < 8; ++i)
        #pragma unroll
        for (int j = 0; j < 4; ++j) acc[i][j] = 0.0f;

    for (int kg = 0; kg < 64; kg += 4) {
        float4 xv[8];
        #pragma unroll
        for (int i = 0; i < 8; ++i)
            xv[i] = *((const float4*)&xs[row0 + i][kg]);
        #pragma unroll
        for (int j = 0; j < 4; ++j) {
            float4 w = ntload4(W + (size_t)(kg + j) * HID);
            #pragma unroll
            for (int i = 0; i < 8; ++i) {
                float xvv = f4c(xv[i], j);
                acc[i][0] = fmaf(xvv, w.x, acc[i][0]);
                acc[i][1] = fmaf(xvv, w.y, acc[i][1]);
                acc[i][2] = fmaf(xvv, w.z, acc[i][2]);
                acc[i][3] = fmaf(xvv, w.w, acc[i][3]);
            }
        }
    }
    float* P = pp + (size_t)(ks * NNEUR + n) * BATCH * HID;
    #pragma unroll
    for (int i = 0; i < 8; ++i)
        *((float4*)(P + (size_t)(row0 + i) * HID + col0)) =
            make_float4(acc[i][0], acc[i][1], acc[i][2], acc[i][3]);
}

// ---------------------------------------------------------------------------
// K2: layer2 at 32 waves/CU via (256,8) + 4x4 tile (hist-style, no spill).
// grid 2048 = n(64) x ct(4: 128 cols) x ks(8: K=64). block 256:
// cg = t&31 (32 x 4 cols = 128), rg = t>>5 (8 x 4 rows = 32).
// p2[8][64][32][512] f32
// ---------------------------------------------------------------------------
__global__ __launch_bounds__(256, 8) void k_layer2(
        const float* __restrict__ pp, const float* __restrict__ phs,
        const float* __restrict__ b1,
        const float* __restrict__ W2, float* __restrict__ p2) {
    const int bid = blockIdx.x;
    const int n  = bid >> 5;
    const int ct = (bid >> 3) & 3;
    const int ks = bid & 7;
    const int t  = threadIdx.x;
    const int cg = t & 31;
    const int rg = t >> 5;
    const int col0 = ct * 128 + cg * 4;
    const int row0 = rg * 4;
    const int k0 = ks * 64;

    const size_t slp = (size_t)NNEUR * BATCH * HID;   // pp slice stride

    __shared__ float xs[BATCH][64];
    #pragma unroll
    for (int q = 0; q < 2; ++q) {                 // 32*16 float4 = 512
        int fi  = t + 256 * q;
        int row = fi >> 4;
        int c4v = fi & 15;
        const float* a = pp + ((size_t)n * BATCH + row) * HID + k0 + c4v * 4;
        float4 s0 = *((const float4*)(a));
        float4 s1 = *((const float4*)(a + slp));
        float4 s2 = *((const float4*)(a + 2 * slp));
        float4 s3 = *((const float4*)(a + 3 * slp));
        float4 hs = *((const float4*)(phs + (size_t)n * HID + k0 + c4v * 4));
        float4 bb = *((const float4*)(b1 + (size_t)n * HID + k0 + c4v * 4));
        *((float4*)&xs[row][c4v * 4]) = make_float4(
            geluf(s0.x + s1.x + s2.x + s3.x + hs.x + bb.x),
            geluf(s0.y + s1.y + s2.y + s3.y + hs.y + bb.y),
            geluf(s0.z + s1.z + s2.z + s3.z + hs.z + bb.z),
            geluf(s0.w + s1.w + s2.w + s3.w + hs.w + bb.w));
    }
    __syncthreads();

    const float* W = W2 + (size_t)n * HID * HID + (size_t)k0 * HID + col0;

    float acc[4][4];
    #pragma unroll
    for (int i = 0; i < 4; ++i)
        #pragma unroll
        for (int j = 0; j < 4; ++j) acc[i][j] = 0.0f;

    for (int kg = 0; kg < 64; kg += 4) {
        float4 xv[4];
        #pragma unroll
        for (int i = 0; i < 4; ++i)
            xv[i] = *((const float4*)&xs[row0 + i][kg]);
        #pragma unroll
        for (int j = 0; j < 4; ++j) {
            float4 w = ntload4(W + (size_t)(kg + j) * HID);
            #pragma unroll
            for (int i = 0; i < 4; ++i) {
                float xvv = f4c(xv[i], j);
                acc[i][0] = fmaf(xvv, w.x, acc[i][0]);
                acc[i][1] = fmaf(xvv, w.y, acc[i][1]);
                acc[i][2] = fmaf(xvv, w.z, acc[i][2]);
                acc[i][3] = fmaf(xvv, w.w, acc[i][3]);
            }
        }
    }
    float* P = p2 + (size_t)(ks * NNEUR + n) * BATCH * HID;
    #pragma unroll
    for (int i = 0; i < 4; ++i)
        *((float4*)(P + (size_t)(row0 + i) * HID + col0)) =
            make_float4(acc[i][0], acc[i][1], acc[i][2], acc[i][3]);
}

// ---------------------------------------------------------------------------
// K3: layer3 at 32 waves/CU via (256,8) + 4x4 tile.
// grid 2048 = n(64) x ct(2: 128 cols) x ks(16: K=32). block 256:
// cg = t&31 (32 x 4 cols = 128), rg = t>>5 (8 x 4 rows = 32).
// p3[16][64][32][256] f32
// ---------------------------------------------------------------------------
__global__ __launch_bounds__(256, 8) void k_layer3(
        const float* __restrict__ p2, const float* __restrict__ b2,
        const float* __restrict__ W3, float* __restrict__ p3) {
    const int bid = blockIdx.x;
    const int n  = bid >> 5;
    const int ct = (bid >> 4) & 1;
    const int ks = bid & 15;
    const int t  = threadIdx.x;
    const int cg = t & 31;
    const int rg = t >> 5;
    const int col0 = ct * 128 + cg * 4;
    const int row0 = rg * 4;
    const int k0 = ks * 32;

    const size_t sl = (size_t)NNEUR * BATCH * HID;

    __shared__ float xs[BATCH][32];
    if (t < 256) {                                // 32*8 float4 = 256
        int row = t >> 3;
        int c4v = t & 7;
        const float* a = p2 + ((size_t)n * BATCH + row) * HID + k0 + c4v * 4;
        float4 s0 = *((const float4*)(a));
        float4 s1 = *((const float4*)(a + sl));
        float4 s2 = *((const float4*)(a + 2 * sl));
        float4 s3 = *((const float4*)(a + 3 * sl));
        float4 s4 = *((const float4*)(a + 4 * sl));
        float4 s5 = *((const float4*)(a + 5 * sl));
        float4 s6 = *((const float4*)(a + 6 * sl));
        float4 s7 = *((const float4*)(a + 7 * sl));
        float4 bb = *((const float4*)(b2 + (size_t)n * HID + k0 + c4v * 4));
        *((float4*)&xs[row][c4v * 4]) = make_float4(
            geluf(s0.x+s1.x+s2.x+s3.x+s4.x+s5.x+s6.x+s7.x + bb.x),
            geluf(s0.y+s1.y+s2.y+s3.y+s4.y+s5.y+s6.y+s7.y + bb.y),
            geluf(s0.z+s1.z+s2.z+s3.z+s4.z+s5.z+s6.z+s7.z + bb.z),
            geluf(s0.w+s1.w+s2.w+s3.w+s4.w+s5.w+s6.w+s7.w + bb.w));
    }
    __syncthreads();

    const float* W = W3 + (size_t)n * HID * MODEL_DIM + (size_t)k0 * MODEL_DIM + col0;

    float acc[4][4];
    #pragma unroll
    for (int i = 0; i < 4; ++i)
        #pragma unroll
        for (int j = 0; j < 4; ++j) acc[i][j] = 0.0f;

    for (int kg = 0; kg < 32; kg += 4) {
        float4 xv[4];
        #pragma unroll
        for (int i = 0; i < 4; ++i)
            xv[i] = *((const float4*)&xs[row0 + i][kg]);
        #pragma unroll
        for (int j = 0; j < 4; ++j) {
            float4 w = ntload4(W + (size_t)(kg + j) * MODEL_DIM);
            #pragma unroll
            for (int i = 0; i < 4; ++i) {
                float xvv = f4c(xv[i], j);
                acc[i][0] = fmaf(xvv, w.x, acc[i][0]);
                acc[i][1] = fmaf(xvv, w.y, acc[i][1]);
                acc[i][2] = fmaf(xvv, w.z, acc[i][2]);
                acc[i][3] = fmaf(xvv, w.w, acc[i][3]);
            }
        }
    }
    float* P = p3 + (size_t)(ks * NNEUR + n) * BATCH * MODEL_DIM;
    #pragma unroll
    for (int i = 0; i < 4; ++i)
        *((float4*)(P + (size_t)(row0 + i) * MODEL_DIM + col0)) =
            make_float4(acc[i][0], acc[i][1], acc[i][2], acc[i][3]);
}

// ---------------------------------------------------------------------------
// K4: y = sum(p3[0..15]) + b3 ; LayerNorm ; oscillator mod ; f32 store
// ---------------------------------------------------------------------------
__global__ __launch_bounds__(256) void k_final(
        const float* __restrict__ p3, const float* __restrict__ b3,
        const float* __restrict__ gamma, const float* __restrict__ beta,
        const int* __restrict__ tick, float* __restrict__ out) {
    const int n  = blockIdx.x >> 3;
    const int bq = blockIdx.x & 7;
    const int t  = threadIdx.x;
    const int w  = t >> 6;
    const int lane = t & 63;
    const int b  = bq * 4 + w;

    const size_t par0 = (size_t)n * MODEL_DIM;
    const size_t rowoff = ((size_t)n * BATCH + b) * MODEL_DIM;
    const size_t sl = (size_t)NNEUR * BATCH * MODEL_DIM;

    float y[4];
    #pragma unroll
    for (int j = 0; j < 4; ++j) {
        int d = lane + 64 * j;
        float v = b3[par0 + d];
        #pragma unroll
        for (int s = 0; s < 16; ++s)
            v += p3[s * sl + rowoff + d];
        y[j] = v;
    }
    float s = y[0] + y[1] + y[2] + y[3];
    #pragma unroll
    for (int off = 32; off > 0; off >>= 1) s += __shfl_xor(s, off);
    float mu = s * (1.0f / 256.0f);
    float q = 0.0f;
    #pragma unroll
    for (int j = 0; j < 4; ++j) { float d0 = y[j] - mu; q = fmaf(d0, d0, q); }
    #pragma unroll
    for (int off = 32; off > 0; off >>= 1) q += __shfl_xor(q, off);
    float inv = rsqrtf(q * (1.0f / 256.0f) + 1e-5f);

    const double TWO_PI = 6.283185307179586476925287;
    double freq  = 0.5 * pow(80.0, (double)n * (1.0 / 63.0));
    double phase = fmod((double)n * 2.3571, TWO_PI);
    double tt    = (double)(*tick) * 0.1;
    float mod = (float)(1.0 + 0.5 * sin(TWO_PI * freq * tt + phase));

    #pragma unroll
    for (int j = 0; j < 4; ++j) {
        int d = lane + 64 * j;
        float o = (y[j] - mu) * inv * gamma[par0 + d] + beta[par0 + d];
        o *= mod;
        out[((size_t)b * NNEUR + n) * MODEL_DIM + d] = o;
    }
}

// ---------------------------------------------------------------------------
extern "C" void kernel_launch(void* const* d_in, const int* in_sizes, int n_in,
                              void* d_out, int out_size, void* d_ws, size_t ws_size,
                              hipStream_t stream) {
    const float* emb  = (const float*)d_in[0];
    const float* pre  = (const float*)d_in[1];
    const float* Wp   = (const float*)d_in[2];
    const float* bp   = (const float*)d_in[3];
    const float* W1   = (const float*)d_in[4];
    const float* b1   = (const float*)d_in[5];
    const float* W2   = (const float*)d_in[6];
    const float* b2   = (const float*)d_in[7];
    const float* W3   = (const float*)d_in[8];
    const float* b3   = (const float*)d_in[9];
    const float* gam  = (const float*)d_in[10];
    const float* bet  = (const float*)d_in[11];
    const int* tick   = (const int*)d_in[12];

    float* ws = (float*)d_ws;
    float* proj = ws;                    // 32*256            =    8192 f32
    float* ph  = proj + 8192;            // [16][64][512]     =  524288 f32
    float* phs = ph + 524288;            // [64][512]         =   32768 f32
    float* pp  = phs + 32768;            // [4][64][32][512]  = 4194304 f32
    float* p2  = pp + 4194304;           // [8][64][32][512]  = 8388608 f32
    float* p3  = p2 + 8388608;           // [16][64][32][256] = 8388608 f32
    float* out = (float*)d_out;

    k_hist   <<<2080, 256, 0, stream>>>(pre, W1, emb, Wp, bp, proj, ph);
    k_proj   <<<512,  256, 0, stream>>>(proj, W1, ph, phs, pp);
    k_layer2 <<<2048, 256, 0, stream>>>(pp, phs, b1, W2, p2);
    k_layer3 <<<2048, 256, 0, stream>>>(p2, b2, W3, p3);
    k_final  <<<512,  256, 0, stream>>>(p3, b3, gam, bet, tick, out);
}

// Round 18
// 147.633 us; speedup vs baseline: 1.2005x; 1.2005x over previous
//
#include <hip/hip_runtime.h>
#include <hip/hip_bf16.h>

#define MODEL_DIM 256
#define HIST 8
#define HID 512
#define NNEUR 64
#define IN_DIM 2304   // MODEL_DIM * (1 + HIST)
#define BATCH 32

typedef float v4f __attribute__((ext_vector_type(4)));

__device__ __forceinline__ float geluf(float x) {
    return 0.5f * x * (1.0f + erff(x * 0.70710678118654752440f));
}
__device__ __forceinline__ float f4c(const float4& v, int j) {
    switch (j) { case 0: return v.x; case 1: return v.y; case 2: return v.z; default: return v.w; }
}
__device__ __forceinline__ float4 ntload4(const float* p) {
    v4f v = __builtin_nontemporal_load((const v4f*)p);
    return make_float4(v.x, v.y, v.z, v.w);
}

// ---------------------------------------------------------------------------
// K1h: history GEMV at 32 waves/CU + build_x merged (r16, unchanged).
// grid 2080, block 256. ph[16][64][512] f32
// ---------------------------------------------------------------------------
__global__ __launch_bounds__(256, 8) void k_hist(
        const float* __restrict__ pre, const float* __restrict__ W1,
        const float* __restrict__ emb, const float* __restrict__ Wp,
        const float* __restrict__ bp, float* __restrict__ proj,
        float* __restrict__ ph) {
    const int bid = blockIdx.x;
    const int t   = threadIdx.x;

    if (bid >= 2048) {
        const int b = bid - 2048;
        __shared__ float e[MODEL_DIM];
        e[t] = emb[b * MODEL_DIM + t];
        __syncthreads();
        float acc = bp[t];
        #pragma unroll 4
        for (int k = 0; k < MODEL_DIM; ++k)
            acc = fmaf(e[k], Wp[(size_t)k * MODEL_DIM + t], acc);
        proj[b * MODEL_DIM + t] = acc;
        return;
    }

    const int n  = bid >> 5;
    const int ks = (bid >> 1) & 15;
    const int ch = bid & 1;
    const int w  = t >> 6;
    const int l  = t & 63;
    const int k0 = ks * 128;
    const int cb = ch * 256;

    __shared__ float ps[128];
    __shared__ float red[4][256];
    if (t < 128) ps[t] = pre[k0 + t];
    __syncthreads();

    const float* W = W1 + (size_t)n * IN_DIM * HID
                        + (size_t)(MODEL_DIM + k0 + w * 32) * HID + cb + l * 4;
    const float* pw = ps + w * 32;

    float4 a = make_float4(0.f, 0.f, 0.f, 0.f);
    #pragma unroll 8
    for (int kk = 0; kk < 32; ++kk) {
        float4 wv = ntload4(W + (size_t)kk * HID);
        float s = pw[kk];
        a.x = fmaf(s, wv.x, a.x);
        a.y = fmaf(s, wv.y, a.y);
        a.z = fmaf(s, wv.z, a.z);
        a.w = fmaf(s, wv.w, a.w);
    }
    *((float4*)&red[w][l * 4]) = a;
    __syncthreads();

    if (t < 64) {
        const int c = t * 4;
        float4 r0 = *((const float4*)&red[0][c]);
        float4 r1 = *((const float4*)&red[1][c]);
        float4 r2 = *((const float4*)&red[2][c]);
        float4 r3 = *((const float4*)&red[3][c]);
        float4 o = make_float4(r0.x + r1.x + r2.x + r3.x,
                               r0.y + r1.y + r2.y + r3.y,
                               r0.z + r1.z + r2.z + r3.z,
                               r0.w + r1.w + r2.w + r3.w);
        *((float4*)(ph + ((size_t)ks * NNEUR + n) * HID + cb + c)) = o;
    }
}

// ---------------------------------------------------------------------------
// K1p: proj GEMM + phs pre-reduction (r16, unchanged).
// grid 512 = n(64) x ct(2) x ks(4: K=64). block 256. pp[4][64][32][512] f32
// ---------------------------------------------------------------------------
__global__ __launch_bounds__(256, 4) void k_proj(
        const float* __restrict__ proj, const float* __restrict__ W1,
        const float* __restrict__ ph, float* __restrict__ phs,
        float* __restrict__ pp) {
    const int bid = blockIdx.x;
    const int t  = threadIdx.x;

    if (bid < 64) {
        const size_t slh = (size_t)NNEUR * HID;
        #pragma unroll
        for (int q = 0; q < 2; ++q) {
            const int c = t + q * 256;
            const float* h = ph + (size_t)bid * HID + c;
            float s = 0.0f;
            #pragma unroll
            for (int s5 = 0; s5 < 16; ++s5)
                s += h[(size_t)s5 * slh];
            phs[(size_t)bid * HID + c] = s;
        }
    }

    const int n  = bid >> 3;
    const int ct = (bid >> 2) & 1;
    const int ks = bid & 3;
    const int cg = t & 63;
    const int rg = t >> 6;
    const int col0 = ct * 256 + cg * 4;
    const int row0 = rg * 8;
    const int k0 = ks * 64;

    __shared__ float xs[BATCH][64];
    #pragma unroll
    for (int q = 0; q < 2; ++q) {                 // 32*16 float4 = 512
        int fi  = t + 256 * q;
        int row = fi >> 4;
        int c4v = fi & 15;
        *((float4*)&xs[row][c4v * 4]) =
            *((const float4*)(proj + (size_t)row * MODEL_DIM + k0 + c4v * 4));
    }
    __syncthreads();

    const float* W = W1 + (size_t)n * IN_DIM * HID + (size_t)k0 * HID + col0;

    float acc[8][4];
    #pragma unroll
    for (int i = 0; i < 8; ++i)
        #pragma unroll
        for (int j = 0; j < 4; ++j) acc[i][j] = 0.0f;

    for (int kg = 0; kg < 64; kg += 4) {
        float4 xv[8];
        #pragma unroll
        for (int i = 0; i < 8; ++i)
            xv[i] = *((const float4*)&xs[row0 + i][kg]);
        #pragma unroll
        for (int j = 0; j < 4; ++j) {
            float4 w = ntload4(W + (size_t)(kg + j) * HID);
            #pragma unroll
            for (int i = 0; i < 8; ++i) {
                float xvv = f4c(xv[i], j);
                acc[i][0] = fmaf(xvv, w.x, acc[i][0]);
                acc[i][1] = fmaf(xvv, w.y, acc[i][1]);
                acc[i][2] = fmaf(xvv, w.z, acc[i][2]);
                acc[i][3] = fmaf(xvv, w.w, acc[i][3]);
            }
        }
    }
    float* P = pp + (size_t)(ks * NNEUR + n) * BATCH * HID;
    #pragma unroll
    for (int i = 0; i < 8; ++i)
        *((float4*)(P + (size_t)(row0 + i) * HID + col0)) =
            make_float4(acc[i][0], acc[i][1], acc[i][2], acc[i][3]);
}

// ---------------------------------------------------------------------------
// K2: layer2 (r16 proven config). grid 1024 = n(64) x ct(2) x ks(8: K=64).
// block 256: cg(64->4 cols) x rg(4->8 rows). p2[8][64][32][512] f32
// ---------------------------------------------------------------------------
__global__ __launch_bounds__(256, 4) void k_layer2(
        const float* __restrict__ pp, const float* __restrict__ phs,
        const float* __restrict__ b1,
        const float* __restrict__ W2, float* __restrict__ p2) {
    const int bid = blockIdx.x;
    const int n  = bid >> 4;
    const int ct = (bid >> 3) & 1;
    const int ks = bid & 7;
    const int t  = threadIdx.x;
    const int cg = t & 63;
    const int rg = t >> 6;
    const int col0 = ct * 256 + cg * 4;
    const int row0 = rg * 8;
    const int k0 = ks * 64;

    const size_t slp = (size_t)NNEUR * BATCH * HID;   // pp slice stride

    __shared__ float xs[BATCH][64];
    #pragma unroll
    for (int q = 0; q < 2; ++q) {                 // 32*16 float4 = 512
        int fi  = t + 256 * q;
        int row = fi >> 4;
        int c4v = fi & 15;
        const float* a = pp + ((size_t)n * BATCH + row) * HID + k0 + c4v * 4;
        float4 s0 = *((const float4*)(a));
        float4 s1 = *((const float4*)(a + slp));
        float4 s2 = *((const float4*)(a + 2 * slp));
        float4 s3 = *((const float4*)(a + 3 * slp));
        float4 hs = *((const float4*)(phs + (size_t)n * HID + k0 + c4v * 4));
        float4 bb = *((const float4*)(b1 + (size_t)n * HID + k0 + c4v * 4));
        *((float4*)&xs[row][c4v * 4]) = make_float4(
            geluf(s0.x + s1.x + s2.x + s3.x + hs.x + bb.x),
            geluf(s0.y + s1.y + s2.y + s3.y + hs.y + bb.y),
            geluf(s0.z + s1.z + s2.z + s3.z + hs.z + bb.z),
            geluf(s0.w + s1.w + s2.w + s3.w + hs.w + bb.w));
    }
    __syncthreads();

    const float* W = W2 + (size_t)n * HID * HID + (size_t)k0 * HID + col0;

    float acc[8][4];
    #pragma unroll
    for (int i = 0; i < 8; ++i)
        #pragma unroll
        for (int j = 0; j < 4; ++j) acc[i][j] = 0.0f;

    for (int kg = 0; kg < 64; kg += 4) {
        float4 xv[8];
        #pragma unroll
        for (int i = 0; i < 8; ++i)
            xv[i] = *((const float4*)&xs[row0 + i][kg]);
        #pragma unroll
        for (int j = 0; j < 4; ++j) {
            float4 w = ntload4(W + (size_t)(kg + j) * HID);
            #pragma unroll
            for (int i = 0; i < 8; ++i) {
                float xvv = f4c(xv[i], j);
                acc[i][0] = fmaf(xvv, w.x, acc[i][0]);
                acc[i][1] = fmaf(xvv, w.y, acc[i][1]);
                acc[i][2] = fmaf(xvv, w.z, acc[i][2]);
                acc[i][3] = fmaf(xvv, w.w, acc[i][3]);
            }
        }
    }
    float* P = p2 + (size_t)(ks * NNEUR + n) * BATCH * HID;
    #pragma unroll
    for (int i = 0; i < 8; ++i)
        *((float4*)(P + (size_t)(row0 + i) * HID + col0)) =
            make_float4(acc[i][0], acc[i][1], acc[i][2], acc[i][3]);
}

// ---------------------------------------------------------------------------
// K3: layer3 (r16 proven config). grid 1024 = n(64) x ks(16: K=32).
// block 256: cg(64 -> 4 cols, all 256) x rg(4 -> 8 rows).
// p3[16][64][32][256] f32
// ---------------------------------------------------------------------------
__global__ __launch_bounds__(256, 4) void k_layer3(
        const float* __restrict__ p2, const float* __restrict__ b2,
        const float* __restrict__ W3, float* __restrict__ p3) {
    const int bid = blockIdx.x;
    const int n  = bid >> 4;
    const int ks = bid & 15;
    const int t  = threadIdx.x;
    const int cg = t & 63;
    const int rg = t >> 6;
    const int col0 = cg * 4;
    const int row0 = rg * 8;
    const int k0 = ks * 32;

    const size_t sl = (size_t)NNEUR * BATCH * HID;

    __shared__ float xs[BATCH][32];
    {                                             // 32*8 float4 = 256
        int row = t >> 3;
        int c4v = t & 7;
        const float* a = p2 + ((size_t)n * BATCH + row) * HID + k0 + c4v * 4;
        float4 s0 = *((const float4*)(a));
        float4 s1 = *((const float4*)(a + sl));
        float4 s2 = *((const float4*)(a + 2 * sl));
        float4 s3 = *((const float4*)(a + 3 * sl));
        float4 s4 = *((const float4*)(a + 4 * sl));
        float4 s5 = *((const float4*)(a + 5 * sl));
        float4 s6 = *((const float4*)(a + 6 * sl));
        float4 s7 = *((const float4*)(a + 7 * sl));
        float4 bb = *((const float4*)(b2 + (size_t)n * HID + k0 + c4v * 4));
        *((float4*)&xs[row][c4v * 4]) = make_float4(
            geluf(s0.x+s1.x+s2.x+s3.x+s4.x+s5.x+s6.x+s7.x + bb.x),
            geluf(s0.y+s1.y+s2.y+s3.y+s4.y+s5.y+s6.y+s7.y + bb.y),
            geluf(s0.z+s1.z+s2.z+s3.z+s4.z+s5.z+s6.z+s7.z + bb.z),
            geluf(s0.w+s1.w+s2.w+s3.w+s4.w+s5.w+s6.w+s7.w + bb.w));
    }
    __syncthreads();

    const float* W = W3 + (size_t)n * HID * MODEL_DIM + (size_t)k0 * MODEL_DIM + col0;

    float acc[8][4];
    #pragma unroll
    for (int i = 0; i < 8; ++i)
        #pragma unroll
        for (int j = 0; j < 4; ++j) acc[i][j] = 0.0f;

    for (int kg = 0; kg < 32; kg += 4) {
        float4 xv[8];
        #pragma unroll
        for (int i = 0; i < 8; ++i)
            xv[i] = *((const float4*)&xs[row0 + i][kg]);
        #pragma unroll
        for (int j = 0; j < 4; ++j) {
            float4 w = ntload4(W + (size_t)(kg + j) * MODEL_DIM);
            #pragma unroll
            for (int i = 0; i < 8; ++i) {
                float xvv = f4c(xv[i], j);
                acc[i][0] = fmaf(xvv, w.x, acc[i][0]);
                acc[i][1] = fmaf(xvv, w.y, acc[i][1]);
                acc[i][2] = fmaf(xvv, w.z, acc[i][2]);
                acc[i][3] = fmaf(xvv, w.w, acc[i][3]);
            }
        }
    }
    float* P = p3 + (size_t)(ks * NNEUR + n) * BATCH * MODEL_DIM;
    #pragma unroll
    for (int i = 0; i < 8; ++i)
        *((float4*)(P + (size_t)(row0 + i) * MODEL_DIM + col0)) =
            make_float4(acc[i][0], acc[i][1], acc[i][2], acc[i][3]);
}

// ---------------------------------------------------------------------------
// K4: y = sum(p3[0..15]) + b3 ; LayerNorm ; oscillator mod ; f32 store
// ---------------------------------------------------------------------------
__global__ __launch_bounds__(256) void k_final(
        const float* __restrict__ p3, const float* __restrict__ b3,
        const float* __restrict__ gamma, const float* __restrict__ beta,
        const int* __restrict__ tick, float* __restrict__ out) {
    const int n  = blockIdx.x >> 3;
    const int bq = blockIdx.x & 7;
    const int t  = threadIdx.x;
    const int w  = t >> 6;
    const int lane = t & 63;
    const int b  = bq * 4 + w;

    const size_t par0 = (size_t)n * MODEL_DIM;
    const size_t rowoff = ((size_t)n * BATCH + b) * MODEL_DIM;
    const size_t sl = (size_t)NNEUR * BATCH * MODEL_DIM;

    float y[4];
    #pragma unroll
    for (int j = 0; j < 4; ++j) {
        int d = lane + 64 * j;
        float v = b3[par0 + d];
        #pragma unroll
        for (int s = 0; s < 16; ++s)
            v += p3[s * sl + rowoff + d];
        y[j] = v;
    }
    float s = y[0] + y[1] + y[2] + y[3];
    #pragma unroll
    for (int off = 32; off > 0; off >>= 1) s += __shfl_xor(s, off);
    float mu = s * (1.0f / 256.0f);
    float q = 0.0f;
    #pragma unroll
    for (int j = 0; j < 4; ++j) { float d0 = y[j] - mu; q = fmaf(d0, d0, q); }
    #pragma unroll
    for (int off = 32; off > 0; off >>= 1) q += __shfl_xor(q, off);
    float inv = rsqrtf(q * (1.0f / 256.0f) + 1e-5f);

    const double TWO_PI = 6.283185307179586476925287;
    double freq  = 0.5 * pow(80.0, (double)n * (1.0 / 63.0));
    double phase = fmod((double)n * 2.3571, TWO_PI);
    double tt    = (double)(*tick) * 0.1;
    float mod = (float)(1.0 + 0.5 * sin(TWO_PI * freq * tt + phase));

    #pragma unroll
    for (int j = 0; j < 4; ++j) {
        int d = lane + 64 * j;
        float o = (y[j] - mu) * inv * gamma[par0 + d] + beta[par0 + d];
        o *= mod;
        out[((size_t)b * NNEUR + n) * MODEL_DIM + d] = o;
    }
}

// ---------------------------------------------------------------------------
extern "C" void kernel_launch(void* const* d_in, const int* in_sizes, int n_in,
                              void* d_out, int out_size, void* d_ws, size_t ws_size,
                              hipStream_t stream) {
    const float* emb  = (const float*)d_in[0];
    const float* pre  = (const float*)d_in[1];
    const float* Wp   = (const float*)d_in[2];
    const float* bp   = (const float*)d_in[3];
    const float* W1   = (const float*)d_in[4];
    const float* b1   = (const float*)d_in[5];
    const float* W2   = (const float*)d_in[6];
    const float* b2   = (const float*)d_in[7];
    const float* W3   = (const float*)d_in[8];
    const float* b3   = (const float*)d_in[9];
    const float* gam  = (const float*)d_in[10];
    const float* bet  = (const float*)d_in[11];
    const int* tick   = (const int*)d_in[12];

    float* ws = (float*)d_ws;
    float* proj = ws;                    // 32*256            =    8192 f32
    float* ph  = proj + 8192;            // [16][64][512]     =  524288 f32
    float* phs = ph + 524288;            // [64][512]         =   32768 f32
    float* pp  = phs + 32768;            // [4][64][32][512]  = 4194304 f32
    float* p2  = pp + 4194304;           // [8][64][32][512]  = 8388608 f32
    float* p3  = p2 + 8388608;           // [16][64][32][256] = 8388608 f32
    float* out = (float*)d_out;

    k_hist   <<<2080, 256, 0, stream>>>(pre, W1, emb, Wp, bp, proj, ph);
    k_proj   <<<512,  256, 0, stream>>>(proj, W1, ph, phs, pp);
    k_layer2 <<<1024, 256, 0, stream>>>(pp, phs, b1, W2, p2);
    k_layer3 <<<1024, 256, 0, stream>>>(p2, b2, W3, p3);
    k_final  <<<512,  256, 0, stream>>>(p3, b3, gam, bet, tick, out);
}

// Round 19
// 137.108 us; speedup vs baseline: 1.2927x; 1.0768x over previous
//
#include <hip/hip_runtime.h>
#include <hip/hip_bf16.h>

#define MODEL_DIM 256
#define HIST 8
#define HID 512
#define NNEUR 64
#define IN_DIM 2304   // MODEL_DIM * (1 + HIST)
#define BATCH 32

typedef float v4f __attribute__((ext_vector_type(4)));

__device__ __forceinline__ float geluf(float x) {
    return 0.5f * x * (1.0f + erff(x * 0.70710678118654752440f));
}
__device__ __forceinline__ float f4c(const float4& v, int j) {
    switch (j) { case 0: return v.x; case 1: return v.y; case 2: return v.z; default: return v.w; }
}
__device__ __forceinline__ float4 ntload4(const float* p) {
    v4f v = __builtin_nontemporal_load((const v4f*)p);
    return make_float4(v.x, v.y, v.z, v.w);
}
// bf16 partials: round-to-nearest-even pack/unpack (partials are finite)
__device__ __forceinline__ unsigned short f2b(float f) {
    unsigned u = __float_as_uint(f);
    u += 0x7FFFu + ((u >> 16) & 1u);
    return (unsigned short)(u >> 16);
}
__device__ __forceinline__ float b2f(unsigned short h) {
    return __uint_as_float(((unsigned)h) << 16);
}
__device__ __forceinline__ ushort4 f4_to_b4(float4 v) {
    return make_ushort4(f2b(v.x), f2b(v.y), f2b(v.z), f2b(v.w));
}
__device__ __forceinline__ float4 b4_to_f4(ushort4 u) {
    return make_float4(b2f(u.x), b2f(u.y), b2f(u.z), b2f(u.w));
}

// ---------------------------------------------------------------------------
// K1h: history GEMV at 32 waves/CU + build_x merged (r18, unchanged).
// grid 2080, block 256. ph[16][64][512] f32
// ---------------------------------------------------------------------------
__global__ __launch_bounds__(256, 8) void k_hist(
        const float* __restrict__ pre, const float* __restrict__ W1,
        const float* __restrict__ emb, const float* __restrict__ Wp,
        const float* __restrict__ bp, float* __restrict__ proj,
        float* __restrict__ ph) {
    const int bid = blockIdx.x;
    const int t   = threadIdx.x;

    if (bid >= 2048) {
        const int b = bid - 2048;
        __shared__ float e[MODEL_DIM];
        e[t] = emb[b * MODEL_DIM + t];
        __syncthreads();
        float acc = bp[t];
        #pragma unroll 4
        for (int k = 0; k < MODEL_DIM; ++k)
            acc = fmaf(e[k], Wp[(size_t)k * MODEL_DIM + t], acc);
        proj[b * MODEL_DIM + t] = acc;
        return;
    }

    const int n  = bid >> 5;
    const int ks = (bid >> 1) & 15;
    const int ch = bid & 1;
    const int w  = t >> 6;
    const int l  = t & 63;
    const int k0 = ks * 128;
    const int cb = ch * 256;

    __shared__ float ps[128];
    __shared__ float red[4][256];
    if (t < 128) ps[t] = pre[k0 + t];
    __syncthreads();

    const float* W = W1 + (size_t)n * IN_DIM * HID
                        + (size_t)(MODEL_DIM + k0 + w * 32) * HID + cb + l * 4;
    const float* pw = ps + w * 32;

    float4 a = make_float4(0.f, 0.f, 0.f, 0.f);
    #pragma unroll 8
    for (int kk = 0; kk < 32; ++kk) {
        float4 wv = ntload4(W + (size_t)kk * HID);
        float s = pw[kk];
        a.x = fmaf(s, wv.x, a.x);
        a.y = fmaf(s, wv.y, a.y);
        a.z = fmaf(s, wv.z, a.z);
        a.w = fmaf(s, wv.w, a.w);
    }
    *((float4*)&red[w][l * 4]) = a;
    __syncthreads();

    if (t < 64) {
        const int c = t * 4;
        float4 r0 = *((const float4*)&red[0][c]);
        float4 r1 = *((const float4*)&red[1][c]);
        float4 r2 = *((const float4*)&red[2][c]);
        float4 r3 = *((const float4*)&red[3][c]);
        float4 o = make_float4(r0.x + r1.x + r2.x + r3.x,
                               r0.y + r1.y + r2.y + r3.y,
                               r0.z + r1.z + r2.z + r3.z,
                               r0.w + r1.w + r2.w + r3.w);
        *((float4*)(ph + ((size_t)ks * NNEUR + n) * HID + cb + c)) = o;
    }
}

// ---------------------------------------------------------------------------
// K1p: proj GEMM + phs pre-reduction (r18 body; pp stored as bf16).
// grid 512 = n(64) x ct(2) x ks(4: K=64). block 256. pp[4][64][32][512] bf16
// ---------------------------------------------------------------------------
__global__ __launch_bounds__(256, 4) void k_proj(
        const float* __restrict__ proj, const float* __restrict__ W1,
        const float* __restrict__ ph, float* __restrict__ phs,
        unsigned short* __restrict__ pp) {
    const int bid = blockIdx.x;
    const int t  = threadIdx.x;

    if (bid < 64) {
        const size_t slh = (size_t)NNEUR * HID;
        #pragma unroll
        for (int q = 0; q < 2; ++q) {
            const int c = t + q * 256;
            const float* h = ph + (size_t)bid * HID + c;
            float s = 0.0f;
            #pragma unroll
            for (int s5 = 0; s5 < 16; ++s5)
                s += h[(size_t)s5 * slh];
            phs[(size_t)bid * HID + c] = s;
        }
    }

    const int n  = bid >> 3;
    const int ct = (bid >> 2) & 1;
    const int ks = bid & 3;
    const int cg = t & 63;
    const int rg = t >> 6;
    const int col0 = ct * 256 + cg * 4;
    const int row0 = rg * 8;
    const int k0 = ks * 64;

    __shared__ float xs[BATCH][64];
    #pragma unroll
    for (int q = 0; q < 2; ++q) {                 // 32*16 float4 = 512
        int fi  = t + 256 * q;
        int row = fi >> 4;
        int c4v = fi & 15;
        *((float4*)&xs[row][c4v * 4]) =
            *((const float4*)(proj + (size_t)row * MODEL_DIM + k0 + c4v * 4));
    }
    __syncthreads();

    const float* W = W1 + (size_t)n * IN_DIM * HID + (size_t)k0 * HID + col0;

    float acc[8][4];
    #pragma unroll
    for (int i = 0; i < 8; ++i)
        #pragma unroll
        for (int j = 0; j < 4; ++j) acc[i][j] = 0.0f;

    for (int kg = 0; kg < 64; kg += 4) {
        float4 xv[8];
        #pragma unroll
        for (int i = 0; i < 8; ++i)
            xv[i] = *((const float4*)&xs[row0 + i][kg]);
        #pragma unroll
        for (int j = 0; j < 4; ++j) {
            float4 w = ntload4(W + (size_t)(kg + j) * HID);
            #pragma unroll
            for (int i = 0; i < 8; ++i) {
                float xvv = f4c(xv[i], j);
                acc[i][0] = fmaf(xvv, w.x, acc[i][0]);
                acc[i][1] = fmaf(xvv, w.y, acc[i][1]);
                acc[i][2] = fmaf(xvv, w.z, acc[i][2]);
                acc[i][3] = fmaf(xvv, w.w, acc[i][3]);
            }
        }
    }
    unsigned short* P = pp + (size_t)(ks * NNEUR + n) * BATCH * HID;
    #pragma unroll
    for (int i = 0; i < 8; ++i)
        *((ushort4*)(P + (size_t)(row0 + i) * HID + col0)) =
            f4_to_b4(make_float4(acc[i][0], acc[i][1], acc[i][2], acc[i][3]));
}

// ---------------------------------------------------------------------------
// K2: layer2 (r18 config; pp read as bf16, p2 stored as bf16).
// grid 1024 = n(64) x ct(2) x ks(8: K=64). block 256.
// p2[8][64][32][512] bf16
// ---------------------------------------------------------------------------
__global__ __launch_bounds__(256, 4) void k_layer2(
        const unsigned short* __restrict__ pp, const float* __restrict__ phs,
        const float* __restrict__ b1,
        const float* __restrict__ W2, unsigned short* __restrict__ p2) {
    const int bid = blockIdx.x;
    const int n  = bid >> 4;
    const int ct = (bid >> 3) & 1;
    const int ks = bid & 7;
    const int t  = threadIdx.x;
    const int cg = t & 63;
    const int rg = t >> 6;
    const int col0 = ct * 256 + cg * 4;
    const int row0 = rg * 8;
    const int k0 = ks * 64;

    const size_t slp = (size_t)NNEUR * BATCH * HID;   // pp slice stride

    __shared__ float xs[BATCH][64];
    #pragma unroll
    for (int q = 0; q < 2; ++q) {                 // 32*16 groups = 512
        int fi  = t + 256 * q;
        int row = fi >> 4;
        int c4v = fi & 15;
        const unsigned short* a = pp + ((size_t)n * BATCH + row) * HID + k0 + c4v * 4;
        float4 s0 = b4_to_f4(*((const ushort4*)(a)));
        float4 s1 = b4_to_f4(*((const ushort4*)(a + slp)));
        float4 s2 = b4_to_f4(*((const ushort4*)(a + 2 * slp)));
        float4 s3 = b4_to_f4(*((const ushort4*)(a + 3 * slp)));
        float4 hs = *((const float4*)(phs + (size_t)n * HID + k0 + c4v * 4));
        float4 bb = *((const float4*)(b1 + (size_t)n * HID + k0 + c4v * 4));
        *((float4*)&xs[row][c4v * 4]) = make_float4(
            geluf(s0.x + s1.x + s2.x + s3.x + hs.x + bb.x),
            geluf(s0.y + s1.y + s2.y + s3.y + hs.y + bb.y),
            geluf(s0.z + s1.z + s2.z + s3.z + hs.z + bb.z),
            geluf(s0.w + s1.w + s2.w + s3.w + hs.w + bb.w));
    }
    __syncthreads();

    const float* W = W2 + (size_t)n * HID * HID + (size_t)k0 * HID + col0;

    float acc[8][4];
    #pragma unroll
    for (int i = 0; i < 8; ++i)
        #pragma unroll
        for (int j = 0; j < 4; ++j) acc[i][j] = 0.0f;

    for (int kg = 0; kg < 64; kg += 4) {
        float4 xv[8];
        #pragma unroll
        for (int i = 0; i < 8; ++i)
            xv[i] = *((const float4*)&xs[row0 + i][kg]);
        #pragma unroll
        for (int j = 0; j < 4; ++j) {
            float4 w = ntload4(W + (size_t)(kg + j) * HID);
            #pragma unroll
            for (int i = 0; i < 8; ++i) {
                float xvv = f4c(xv[i], j);
                acc[i][0] = fmaf(xvv, w.x, acc[i][0]);
                acc[i][1] = fmaf(xvv, w.y, acc[i][1]);
                acc[i][2] = fmaf(xvv, w.z, acc[i][2]);
                acc[i][3] = fmaf(xvv, w.w, acc[i][3]);
            }
        }
    }
    unsigned short* P = p2 + (size_t)(ks * NNEUR + n) * BATCH * HID;
    #pragma unroll
    for (int i = 0; i < 8; ++i)
        *((ushort4*)(P + (size_t)(row0 + i) * HID + col0)) =
            f4_to_b4(make_float4(acc[i][0], acc[i][1], acc[i][2], acc[i][3]));
}

// ---------------------------------------------------------------------------
// K3: layer3 (r18 config; p2 read as bf16, p3 stored as bf16).
// grid 1024 = n(64) x ks(16: K=32). block 256.
// p3[16][64][32][256] bf16
// ---------------------------------------------------------------------------
__global__ __launch_bounds__(256, 4) void k_layer3(
        const unsigned short* __restrict__ p2, const float* __restrict__ b2,
        const float* __restrict__ W3, unsigned short* __restrict__ p3) {
    const int bid = blockIdx.x;
    const int n  = bid >> 4;
    const int ks = bid & 15;
    const int t  = threadIdx.x;
    const int cg = t & 63;
    const int rg = t >> 6;
    const int col0 = cg * 4;
    const int row0 = rg * 8;
    const int k0 = ks * 32;

    const size_t sl = (size_t)NNEUR * BATCH * HID;

    __shared__ float xs[BATCH][32];
    {                                             // 32*8 groups = 256
        int row = t >> 3;
        int c4v = t & 7;
        const unsigned short* a = p2 + ((size_t)n * BATCH + row) * HID + k0 + c4v * 4;
        float4 s0 = b4_to_f4(*((const ushort4*)(a)));
        float4 s1 = b4_to_f4(*((const ushort4*)(a + sl)));
        float4 s2 = b4_to_f4(*((const ushort4*)(a + 2 * sl)));
        float4 s3 = b4_to_f4(*((const ushort4*)(a + 3 * sl)));
        float4 s4 = b4_to_f4(*((const ushort4*)(a + 4 * sl)));
        float4 s5 = b4_to_f4(*((const ushort4*)(a + 5 * sl)));
        float4 s6 = b4_to_f4(*((const ushort4*)(a + 6 * sl)));
        float4 s7 = b4_to_f4(*((const ushort4*)(a + 7 * sl)));
        float4 bb = *((const float4*)(b2 + (size_t)n * HID + k0 + c4v * 4));
        *((float4*)&xs[row][c4v * 4]) = make_float4(
            geluf(s0.x+s1.x+s2.x+s3.x+s4.x+s5.x+s6.x+s7.x + bb.x),
            geluf(s0.y+s1.y+s2.y+s3.y+s4.y+s5.y+s6.y+s7.y + bb.y),
            geluf(s0.z+s1.z+s2.z+s3.z+s4.z+s5.z+s6.z+s7.z + bb.z),
            geluf(s0.w+s1.w+s2.w+s3.w+s4.w+s5.w+s6.w+s7.w + bb.w));
    }
    __syncthreads();

    const float* W = W3 + (size_t)n * HID * MODEL_DIM + (size_t)k0 * MODEL_DIM + col0;

    float acc[8][4];
    #pragma unroll
    for (int i = 0; i < 8; ++i)
        #pragma unroll
        for (int j = 0; j < 4; ++j) acc[i][j] = 0.0f;

    for (int kg = 0; kg < 32; kg += 4) {
        float4 xv[8];
        #pragma unroll
        for (int i = 0; i < 8; ++i)
            xv[i] = *((const float4*)&xs[row0 + i][kg]);
        #pragma unroll
        for (int j = 0; j < 4; ++j) {
            float4 w = ntload4(W + (size_t)(kg + j) * MODEL_DIM);
            #pragma unroll
            for (int i = 0; i < 8; ++i) {
                float xvv = f4c(xv[i], j);
                acc[i][0] = fmaf(xvv, w.x, acc[i][0]);
                acc[i][1] = fmaf(xvv, w.y, acc[i][1]);
                acc[i][2] = fmaf(xvv, w.z, acc[i][2]);
                acc[i][3] = fmaf(xvv, w.w, acc[i][3]);
            }
        }
    }
    unsigned short* P = p3 + (size_t)(ks * NNEUR + n) * BATCH * MODEL_DIM;
    #pragma unroll
    for (int i = 0; i < 8; ++i)
        *((ushort4*)(P + (size_t)(row0 + i) * MODEL_DIM + col0)) =
            f4_to_b4(make_float4(acc[i][0], acc[i][1], acc[i][2], acc[i][3]));
}

// ---------------------------------------------------------------------------
// K4: y = sum(p3[0..15] bf16) + b3 ; LayerNorm ; oscillator mod ; f32 store
// ---------------------------------------------------------------------------
__global__ __launch_bounds__(256) void k_final(
        const unsigned short* __restrict__ p3, const float* __restrict__ b3,
        const float* __restrict__ gamma, const float* __restrict__ beta,
        const int* __restrict__ tick, float* __restrict__ out) {
    const int n  = blockIdx.x >> 3;
    const int bq = blockIdx.x & 7;
    const int t  = threadIdx.x;
    const int w  = t >> 6;
    const int lane = t & 63;
    const int b  = bq * 4 + w;

    const size_t par0 = (size_t)n * MODEL_DIM;
    const size_t rowoff = ((size_t)n * BATCH + b) * MODEL_DIM;
    const size_t sl = (size_t)NNEUR * BATCH * MODEL_DIM;

    float y[4];
    #pragma unroll
    for (int j = 0; j < 4; ++j) {
        int d = lane + 64 * j;
        float v = b3[par0 + d];
        #pragma unroll
        for (int s = 0; s < 16; ++s)
            v += b2f(p3[s * sl + rowoff + d]);
        y[j] = v;
    }
    float s = y[0] + y[1] + y[2] + y[3];
    #pragma unroll
    for (int off = 32; off > 0; off >>= 1) s += __shfl_xor(s, off);
    float mu = s * (1.0f / 256.0f);
    float q = 0.0f;
    #pragma unroll
    for (int j = 0; j < 4; ++j) { float d0 = y[j] - mu; q = fmaf(d0, d0, q); }
    #pragma unroll
    for (int off = 32; off > 0; off >>= 1) q += __shfl_xor(q, off);
    float inv = rsqrtf(q * (1.0f / 256.0f) + 1e-5f);

    const double TWO_PI = 6.283185307179586476925287;
    double freq  = 0.5 * pow(80.0, (double)n * (1.0 / 63.0));
    double phase = fmod((double)n * 2.3571, TWO_PI);
    double tt    = (double)(*tick) * 0.1;
    float mod = (float)(1.0 + 0.5 * sin(TWO_PI * freq * tt + phase));

    #pragma unroll
    for (int j = 0; j < 4; ++j) {
        int d = lane + 64 * j;
        float o = (y[j] - mu) * inv * gamma[par0 + d] + beta[par0 + d];
        o *= mod;
        out[((size_t)b * NNEUR + n) * MODEL_DIM + d] = o;
    }
}

// ---------------------------------------------------------------------------
extern "C" void kernel_launch(void* const* d_in, const int* in_sizes, int n_in,
                              void* d_out, int out_size, void* d_ws, size_t ws_size,
                              hipStream_t stream) {
    const float* emb  = (const float*)d_in[0];
    const float* pre  = (const float*)d_in[1];
    const float* Wp   = (const float*)d_in[2];
    const float* bp   = (const float*)d_in[3];
    const float* W1   = (const float*)d_in[4];
    const float* b1   = (const float*)d_in[5];
    const float* W2   = (const float*)d_in[6];
    const float* b2   = (const float*)d_in[7];
    const float* W3   = (const float*)d_in[8];
    const float* b3   = (const float*)d_in[9];
    const float* gam  = (const float*)d_in[10];
    const float* bet  = (const float*)d_in[11];
    const int* tick   = (const int*)d_in[12];

    float* ws = (float*)d_ws;
    float* proj = ws;                            // 32*256            =    8192 f32
    float* ph  = proj + 8192;                    // [16][64][512]     =  524288 f32
    float* phs = ph + 524288;                    // [64][512]         =   32768 f32
    unsigned short* pp = (unsigned short*)(phs + 32768);  // [4][64][32][512]  bf16 (8MB)
    unsigned short* p2 = pp + 4194304;           // [8][64][32][512]  bf16 (16MB)
    unsigned short* p3 = p2 + 8388608;           // [16][64][32][256] bf16 (16MB)
    float* out = (float*)d_out;

    k_hist   <<<2080, 256, 0, stream>>>(pre, W1, emb, Wp, bp, proj, ph);
    k_proj   <<<512,  256, 0, stream>>>(proj, W1, ph, phs, pp);
    k_layer2 <<<1024, 256, 0, stream>>>(pp, phs, b1, W2, p2);
    k_layer3 <<<1024, 256, 0, stream>>>(p2, b2, W3, p3);
    k_final  <<<512,  256, 0, stream>>>(p3, b3, gam, bet, tick, out);
}

// Round 20
// 136.092 us; speedup vs baseline: 1.3023x; 1.0075x over previous
//
#include <hip/hip_runtime.h>
#include <hip/hip_bf16.h>

#define MODEL_DIM 256
#define HIST 8
#define HID 512
#define NNEUR 64
#define IN_DIM 2304   // MODEL_DIM * (1 + HIST)
#define BATCH 32

typedef float v4f __attribute__((ext_vector_type(4)));
typedef const __attribute__((address_space(1))) void* gptr_t;
typedef __attribute__((address_space(3))) void* lptr_t;

__device__ __forceinline__ float geluf(float x) {
    return 0.5f * x * (1.0f + erff(x * 0.70710678118654752440f));
}
__device__ __forceinline__ float f4c(const float4& v, int j) {
    switch (j) { case 0: return v.x; case 1: return v.y; case 2: return v.z; default: return v.w; }
}
__device__ __forceinline__ float4 ntload4(const float* p) {
    v4f v = __builtin_nontemporal_load((const v4f*)p);
    return make_float4(v.x, v.y, v.z, v.w);
}
// async global->LDS, 16B per lane, LDS dest = wave-uniform base + lane*16
__device__ __forceinline__ void gll16(const float* g, float* l) {
    __builtin_amdgcn_global_load_lds((gptr_t)g, (lptr_t)l, 16, 0, 0);
}
// bf16 partials: round-to-nearest-even pack/unpack (partials are finite)
__device__ __forceinline__ unsigned short f2b(float f) {
    unsigned u = __float_as_uint(f);
    u += 0x7FFFu + ((u >> 16) & 1u);
    return (unsigned short)(u >> 16);
}
__device__ __forceinline__ float b2f(unsigned short h) {
    return __uint_as_float(((unsigned)h) << 16);
}
__device__ __forceinline__ ushort4 f4_to_b4(float4 v) {
    return make_ushort4(f2b(v.x), f2b(v.y), f2b(v.z), f2b(v.w));
}
__device__ __forceinline__ float4 b4_to_f4(ushort4 u) {
    return make_float4(b2f(u.x), b2f(u.y), b2f(u.z), b2f(u.w));
}

// ---------------------------------------------------------------------------
// K1h: history GEMV, async global_load_lds pipeline (2-deep, 4 rows x 1KB per
// batch, per-wave-private LDS buffers, vmcnt(4) steady state) + build_x merged.
// grid 2080, block 256 = 4 waves. Each wave: rows k0+32w..+32, 256-col half.
// FMA order per lane identical to r19 -> bit-identical ph.
// ph[16][64][512] f32
// ---------------------------------------------------------------------------
__global__ __launch_bounds__(256, 4) void k_hist(
        const float* __restrict__ pre, const float* __restrict__ W1,
        const float* __restrict__ emb, const float* __restrict__ Wp,
        const float* __restrict__ bp, float* __restrict__ proj,
        float* __restrict__ ph) {
    const int bid = blockIdx.x;
    const int t   = threadIdx.x;

    __shared__ float ps[128];
    __shared__ float red[4][256];
    __shared__ float wbuf[4][2][4][256];   // [wave][buf][row][col] = 32 KB

    if (bid >= 2048) {
        const int b = bid - 2048;
        __shared__ float e[MODEL_DIM];
        e[t] = emb[b * MODEL_DIM + t];
        __syncthreads();
        float acc = bp[t];
        #pragma unroll 4
        for (int k = 0; k < MODEL_DIM; ++k)
            acc = fmaf(e[k], Wp[(size_t)k * MODEL_DIM + t], acc);
        proj[b * MODEL_DIM + t] = acc;
        return;
    }

    const int n  = bid >> 5;
    const int ks = (bid >> 1) & 15;
    const int ch = bid & 1;
    const int w  = t >> 6;
    const int l  = t & 63;
    const int k0 = ks * 128;
    const int cb = ch * 256;

    if (t < 128) ps[t] = pre[k0 + t];
    __syncthreads();

    const float* Wb = W1 + (size_t)n * IN_DIM * HID
                         + (size_t)(MODEL_DIM + k0 + w * 32) * HID + cb;
    const float* gl = Wb + l * 4;          // per-lane global addr (16B/lane)
    const float* pw = ps + w * 32;
    float* buf0 = &wbuf[w][0][0][0];       // wave-private buffers
    float* buf1 = &wbuf[w][1][0][0];

    // prologue: issue batch 0 (rows 0..3)
    #pragma unroll
    for (int r = 0; r < 4; ++r)
        gll16(gl + (size_t)r * HID, buf0 + r * 256);

    float4 a = make_float4(0.f, 0.f, 0.f, 0.f);
    #pragma unroll
    for (int bi = 0; bi < 8; ++bi) {
        float* cur = (bi & 1) ? buf1 : buf0;   // compile-time under unroll
        float* nxt = (bi & 1) ? buf0 : buf1;
        if (bi < 7) {
            #pragma unroll
            for (int r = 0; r < 4; ++r)
                gll16(gl + (size_t)((bi + 1) * 4 + r) * HID, nxt + r * 256);
            // 8 outstanding; wait until 4 remain -> current batch landed
            asm volatile("s_waitcnt vmcnt(4)" ::: "memory");
        } else {
            asm volatile("s_waitcnt vmcnt(0)" ::: "memory");
        }
        __builtin_amdgcn_sched_barrier(0);
        #pragma unroll
        for (int r = 0; r < 4; ++r) {
            float s = pw[bi * 4 + r];
            float4 wv = *((const float4*)(cur + r * 256 + l * 4));
            a.x = fmaf(s, wv.x, a.x);
            a.y = fmaf(s, wv.y, a.y);
            a.z = fmaf(s, wv.z, a.z);
            a.w = fmaf(s, wv.w, a.w);
        }
    }

    *((float4*)&red[w][l * 4]) = a;
    __syncthreads();

    if (t < 64) {
        const int c = t * 4;
        float4 r0 = *((const float4*)&red[0][c]);
        float4 r1 = *((const float4*)&red[1][c]);
        float4 r2 = *((const float4*)&red[2][c]);
        float4 r3 = *((const float4*)&red[3][c]);
        float4 o = make_float4(r0.x + r1.x + r2.x + r3.x,
                               r0.y + r1.y + r2.y + r3.y,
                               r0.z + r1.z + r2.z + r3.z,
                               r0.w + r1.w + r2.w + r3.w);
        *((float4*)(ph + ((size_t)ks * NNEUR + n) * HID + cb + c)) = o;
    }
}

// ---------------------------------------------------------------------------
// K1p: proj GEMM + phs pre-reduction (r19, unchanged).
// grid 512 = n(64) x ct(2) x ks(4: K=64). block 256. pp[4][64][32][512] bf16
// ---------------------------------------------------------------------------
__global__ __launch_bounds__(256, 4) void k_proj(
        const float* __restrict__ proj, const float* __restrict__ W1,
        const float* __restrict__ ph, float* __restrict__ phs,
        unsigned short* __restrict__ pp) {
    const int bid = blockIdx.x;
    const int t  = threadIdx.x;

    if (bid < 64) {
        const size_t slh = (size_t)NNEUR * HID;
        #pragma unroll
        for (int q = 0; q < 2; ++q) {
            const int c = t + q * 256;
            const float* h = ph + (size_t)bid * HID + c;
            float s = 0.0f;
            #pragma unroll
            for (int s5 = 0; s5 < 16; ++s5)
                s += h[(size_t)s5 * slh];
            phs[(size_t)bid * HID + c] = s;
        }
    }

    const int n  = bid >> 3;
    const int ct = (bid >> 2) & 1;
    const int ks = bid & 3;
    const int cg = t & 63;
    const int rg = t >> 6;
    const int col0 = ct * 256 + cg * 4;
    const int row0 = rg * 8;
    const int k0 = ks * 64;

    __shared__ float xs[BATCH][64];
    #pragma unroll
    for (int q = 0; q < 2; ++q) {                 // 32*16 float4 = 512
        int fi  = t + 256 * q;
        int row = fi >> 4;
        int c4v = fi & 15;
        *((float4*)&xs[row][c4v * 4]) =
            *((const float4*)(proj + (size_t)row * MODEL_DIM + k0 + c4v * 4));
    }
    __syncthreads();

    const float* W = W1 + (size_t)n * IN_DIM * HID + (size_t)k0 * HID + col0;

    float acc[8][4];
    #pragma unroll
    for (int i = 0; i < 8; ++i)
        #pragma unroll
        for (int j = 0; j < 4; ++j) acc[i][j] = 0.0f;

    for (int kg = 0; kg < 64; kg += 4) {
        float4 xv[8];
        #pragma unroll
        for (int i = 0; i < 8; ++i)
            xv[i] = *((const float4*)&xs[row0 + i][kg]);
        #pragma unroll
        for (int j = 0; j < 4; ++j) {
            float4 w = ntload4(W + (size_t)(kg + j) * HID);
            #pragma unroll
            for (int i = 0; i < 8; ++i) {
                float xvv = f4c(xv[i], j);
                acc[i][0] = fmaf(xvv, w.x, acc[i][0]);
                acc[i][1] = fmaf(xvv, w.y, acc[i][1]);
                acc[i][2] = fmaf(xvv, w.z, acc[i][2]);
                acc[i][3] = fmaf(xvv, w.w, acc[i][3]);
            }
        }
    }
    unsigned short* P = pp + (size_t)(ks * NNEUR + n) * BATCH * HID;
    #pragma unroll
    for (int i = 0; i < 8; ++i)
        *((ushort4*)(P + (size_t)(row0 + i) * HID + col0)) =
            f4_to_b4(make_float4(acc[i][0], acc[i][1], acc[i][2], acc[i][3]));
}

// ---------------------------------------------------------------------------
// K2: layer2 (r19, unchanged). grid 1024 = n(64) x ct(2) x ks(8: K=64).
// block 256. p2[8][64][32][512] bf16
// ---------------------------------------------------------------------------
__global__ __launch_bounds__(256, 4) void k_layer2(
        const unsigned short* __restrict__ pp, const float* __restrict__ phs,
        const float* __restrict__ b1,
        const float* __restrict__ W2, unsigned short* __restrict__ p2) {
    const int bid = blockIdx.x;
    const int n  = bid >> 4;
    const int ct = (bid >> 3) & 1;
    const int ks = bid & 7;
    const int t  = threadIdx.x;
    const int cg = t & 63;
    const int rg = t >> 6;
    const int col0 = ct * 256 + cg * 4;
    const int row0 = rg * 8;
    const int k0 = ks * 64;

    const size_t slp = (size_t)NNEUR * BATCH * HID;   // pp slice stride

    __shared__ float xs[BATCH][64];
    #pragma unroll
    for (int q = 0; q < 2; ++q) {                 // 32*16 groups = 512
        int fi  = t + 256 * q;
        int row = fi >> 4;
        int c4v = fi & 15;
        const unsigned short* a = pp + ((size_t)n * BATCH + row) * HID + k0 + c4v * 4;
        float4 s0 = b4_to_f4(*((const ushort4*)(a)));
        float4 s1 = b4_to_f4(*((const ushort4*)(a + slp)));
        float4 s2 = b4_to_f4(*((const ushort4*)(a + 2 * slp)));
        float4 s3 = b4_to_f4(*((const ushort4*)(a + 3 * slp)));
        float4 hs = *((const float4*)(phs + (size_t)n * HID + k0 + c4v * 4));
        float4 bb = *((const float4*)(b1 + (size_t)n * HID + k0 + c4v * 4));
        *((float4*)&xs[row][c4v * 4]) = make_float4(
            geluf(s0.x + s1.x + s2.x + s3.x + hs.x + bb.x),
            geluf(s0.y + s1.y + s2.y + s3.y + hs.y + bb.y),
            geluf(s0.z + s1.z + s2.z + s3.z + hs.z + bb.z),
            geluf(s0.w + s1.w + s2.w + s3.w + hs.w + bb.w));
    }
    __syncthreads();

    const float* W = W2 + (size_t)n * HID * HID + (size_t)k0 * HID + col0;

    float acc[8][4];
    #pragma unroll
    for (int i = 0; i < 8; ++i)
        #pragma unroll
        for (int j = 0; j < 4; ++j) acc[i][j] = 0.0f;

    for (int kg = 0; kg < 64; kg += 4) {
        float4 xv[8];
        #pragma unroll
        for (int i = 0; i < 8; ++i)
            xv[i] = *((const float4*)&xs[row0 + i][kg]);
        #pragma unroll
        for (int j = 0; j < 4; ++j) {
            float4 w = ntload4(W + (size_t)(kg + j) * HID);
            #pragma unroll
            for (int i = 0; i < 8; ++i) {
                float xvv = f4c(xv[i], j);
                acc[i][0] = fmaf(xvv, w.x, acc[i][0]);
                acc[i][1] = fmaf(xvv, w.y, acc[i][1]);
                acc[i][2] = fmaf(xvv, w.z, acc[i][2]);
                acc[i][3] = fmaf(xvv, w.w, acc[i][3]);
            }
        }
    }
    unsigned short* P = p2 + (size_t)(ks * NNEUR + n) * BATCH * HID;
    #pragma unroll
    for (int i = 0; i < 8; ++i)
        *((ushort4*)(P + (size_t)(row0 + i) * HID + col0)) =
            f4_to_b4(make_float4(acc[i][0], acc[i][1], acc[i][2], acc[i][3]));
}

// ---------------------------------------------------------------------------
// K3: layer3 (r19, unchanged). grid 1024 = n(64) x ks(16: K=32). block 256.
// p3[16][64][32][256] bf16
// ---------------------------------------------------------------------------
__global__ __launch_bounds__(256, 4) void k_layer3(
        const unsigned short* __restrict__ p2, const float* __restrict__ b2,
        const float* __restrict__ W3, unsigned short* __restrict__ p3) {
    const int bid = blockIdx.x;
    const int n  = bid >> 4;
    const int ks = bid & 15;
    const int t  = threadIdx.x;
    const int cg = t & 63;
    const int rg = t >> 6;
    const int col0 = cg * 4;
    const int row0 = rg * 8;
    const int k0 = ks * 32;

    const size_t sl = (size_t)NNEUR * BATCH * HID;

    __shared__ float xs[BATCH][32];
    {                                             // 32*8 groups = 256
        int row = t >> 3;
        int c4v = t & 7;
        const unsigned short* a = p2 + ((size_t)n * BATCH + row) * HID + k0 + c4v * 4;
        float4 s0 = b4_to_f4(*((const ushort4*)(a)));
        float4 s1 = b4_to_f4(*((const ushort4*)(a + sl)));
        float4 s2 = b4_to_f4(*((const ushort4*)(a + 2 * sl)));
        float4 s3 = b4_to_f4(*((const ushort4*)(a + 3 * sl)));
        float4 s4 = b4_to_f4(*((const ushort4*)(a + 4 * sl)));
        float4 s5 = b4_to_f4(*((const ushort4*)(a + 5 * sl)));
        float4 s6 = b4_to_f4(*((const ushort4*)(a + 6 * sl)));
        float4 s7 = b4_to_f4(*((const ushort4*)(a + 7 * sl)));
        float4 bb = *((const float4*)(b2 + (size_t)n * HID + k0 + c4v * 4));
        *((float4*)&xs[row][c4v * 4]) = make_float4(
            geluf(s0.x+s1.x+s2.x+s3.x+s4.x+s5.x+s6.x+s7.x + bb.x),
            geluf(s0.y+s1.y+s2.y+s3.y+s4.y+s5.y+s6.y+s7.y + bb.y),
            geluf(s0.z+s1.z+s2.z+s3.z+s4.z+s5.z+s6.z+s7.z + bb.z),
            geluf(s0.w+s1.w+s2.w+s3.w+s4.w+s5.w+s6.w+s7.w + bb.w));
    }
    __syncthreads();

    const float* W = W3 + (size_t)n * HID * MODEL_DIM + (size_t)k0 * MODEL_DIM + col0;

    float acc[8][4];
    #pragma unroll
    for (int i = 0; i < 8; ++i)
        #pragma unroll
        for (int j = 0; j < 4; ++j) acc[i][j] = 0.0f;

    for (int kg = 0; kg < 32; kg += 4) {
        float4 xv[8];
        #pragma unroll
        for (int i = 0; i < 8; ++i)
            xv[i] = *((const float4*)&xs[row0 + i][kg]);
        #pragma unroll
        for (int j = 0; j < 4; ++j) {
            float4 w = ntload4(W + (size_t)(kg + j) * MODEL_DIM);
            #pragma unroll
            for (int i = 0; i < 8; ++i) {
                float xvv = f4c(xv[i], j);
                acc[i][0] = fmaf(xvv, w.x, acc[i][0]);
                acc[i][1] = fmaf(xvv, w.y, acc[i][1]);
                acc[i][2] = fmaf(xvv, w.z, acc[i][2]);
                acc[i][3] = fmaf(xvv, w.w, acc[i][3]);
            }
        }
    }
    unsigned short* P = p3 + (size_t)(ks * NNEUR + n) * BATCH * MODEL_DIM;
    #pragma unroll
    for (int i = 0; i < 8; ++i)
        *((ushort4*)(P + (size_t)(row0 + i) * MODEL_DIM + col0)) =
            f4_to_b4(make_float4(acc[i][0], acc[i][1], acc[i][2], acc[i][3]));
}

// ---------------------------------------------------------------------------
// K4: y = sum(p3[0..15] bf16) + b3 ; LayerNorm ; oscillator mod ; f32 store
// ---------------------------------------------------------------------------
__global__ __launch_bounds__(256) void k_final(
        const unsigned short* __restrict__ p3, const float* __restrict__ b3,
        const float* __restrict__ gamma, const float* __restrict__ beta,
        const int* __restrict__ tick, float* __restrict__ out) {
    const int n  = blockIdx.x >> 3;
    const int bq = blockIdx.x & 7;
    const int t  = threadIdx.x;
    const int w  = t >> 6;
    const int lane = t & 63;
    const int b  = bq * 4 + w;

    const size_t par0 = (size_t)n * MODEL_DIM;
    const size_t rowoff = ((size_t)n * BATCH + b) * MODEL_DIM;
    const size_t sl = (size_t)NNEUR * BATCH * MODEL_DIM;

    float y[4];
    #pragma unroll
    for (int j = 0; j < 4; ++j) {
        int d = lane + 64 * j;
        float v = b3[par0 + d];
        #pragma unroll
        for (int s = 0; s < 16; ++s)
            v += b2f(p3[s * sl + rowoff + d]);
        y[j] = v;
    }
    float s = y[0] + y[1] + y[2] + y[3];
    #pragma unroll
    for (int off = 32; off > 0; off >>= 1) s += __shfl_xor(s, off);
    float mu = s * (1.0f / 256.0f);
    float q = 0.0f;
    #pragma unroll
    for (int j = 0; j < 4; ++j) { float d0 = y[j] - mu; q = fmaf(d0, d0, q); }
    #pragma unroll
    for (int off = 32; off > 0; off >>= 1) q += __shfl_xor(q, off);
    float inv = rsqrtf(q * (1.0f / 256.0f) + 1e-5f);

    const double TWO_PI = 6.283185307179586476925287;
    double freq  = 0.5 * pow(80.0, (double)n * (1.0 / 63.0));
    double phase = fmod((double)n * 2.3571, TWO_PI);
    double tt    = (double)(*tick) * 0.1;
    float mod = (float)(1.0 + 0.5 * sin(TWO_PI * freq * tt + phase));

    #pragma unroll
    for (int j = 0; j < 4; ++j) {
        int d = lane + 64 * j;
        float o = (y[j] - mu) * inv * gamma[par0 + d] + beta[par0 + d];
        o *= mod;
        out[((size_t)b * NNEUR + n) * MODEL_DIM + d] = o;
    }
}

// ---------------------------------------------------------------------------
extern "C" void kernel_launch(void* const* d_in, const int* in_sizes, int n_in,
                              void* d_out, int out_size, void* d_ws, size_t ws_size,
                              hipStream_t stream) {
    const float* emb  = (const float*)d_in[0];
    const float* pre  = (const float*)d_in[1];
    const float* Wp   = (const float*)d_in[2];
    const float* bp   = (const float*)d_in[3];
    const float* W1   = (const float*)d_in[4];
    const float* b1   = (const float*)d_in[5];
    const float* W2   = (const float*)d_in[6];
    const float* b2   = (const float*)d_in[7];
    const float* W3   = (const float*)d_in[8];
    const float* b3   = (const float*)d_in[9];
    const float* gam  = (const float*)d_in[10];
    const float* bet  = (const float*)d_in[11];
    const int* tick   = (const int*)d_in[12];

    float* ws = (float*)d_ws;
    float* proj = ws;                            // 32*256            =    8192 f32
    float* ph  = proj + 8192;                    // [16][64][512]     =  524288 f32
    float* phs = ph + 524288;                    // [64][512]         =   32768 f32
    unsigned short* pp = (unsigned short*)(phs + 32768);  // [4][64][32][512]  bf16 (8MB)
    unsigned short* p2 = pp + 4194304;           // [8][64][32][512]  bf16 (16MB)
    unsigned short* p3 = p2 + 8388608;           // [16][64][32][256] bf16 (16MB)
    float* out = (float*)d_out;

    k_hist   <<<2080, 256, 0, stream>>>(pre, W1, emb, Wp, bp, proj, ph);
    k_proj   <<<512,  256, 0, stream>>>(proj, W1, ph, phs, pp);
    k_layer2 <<<1024, 256, 0, stream>>>(pp, phs, b1, W2, p2);
    k_layer3 <<<1024, 256, 0, stream>>>(p2, b2, W3, p3);
    k_final  <<<512,  256, 0, stream>>>(p3, b3, gam, bet, tick, out);
}

// Round 21
// 135.092 us; speedup vs baseline: 1.3119x; 1.0074x over previous
//
#include <hip/hip_runtime.h>
#include <hip/hip_bf16.h>

#define MODEL_DIM 256
#define HIST 8
#define HID 512
#define NNEUR 64
#define IN_DIM 2304   // MODEL_DIM * (1 + HIST)
#define BATCH 32

typedef float v4f __attribute__((ext_vector_type(4)));
typedef const __attribute__((address_space(1))) void* gptr_t;
typedef __attribute__((address_space(3))) void* lptr_t;

__device__ __forceinline__ float geluf(float x) {
    return 0.5f * x * (1.0f + erff(x * 0.70710678118654752440f));
}
__device__ __forceinline__ float f4c(const float4& v, int j) {
    switch (j) { case 0: return v.x; case 1: return v.y; case 2: return v.z; default: return v.w; }
}
__device__ __forceinline__ float4 ntload4(const float* p) {
    v4f v = __builtin_nontemporal_load((const v4f*)p);
    return make_float4(v.x, v.y, v.z, v.w);
}
// async global->LDS, 16B per lane, LDS dest = wave-uniform base + lane*16
__device__ __forceinline__ void gll16(const float* g, float* l) {
    __builtin_amdgcn_global_load_lds((gptr_t)g, (lptr_t)l, 16, 0, 0);
}
// bf16 partials: round-to-nearest-even pack/unpack (partials are finite)
__device__ __forceinline__ unsigned short f2b(float f) {
    unsigned u = __float_as_uint(f);
    u += 0x7FFFu + ((u >> 16) & 1u);
    return (unsigned short)(u >> 16);
}
__device__ __forceinline__ float b2f(unsigned short h) {
    return __uint_as_float(((unsigned)h) << 16);
}
__device__ __forceinline__ ushort4 f4_to_b4(float4 v) {
    return make_ushort4(f2b(v.x), f2b(v.y), f2b(v.z), f2b(v.w));
}
__device__ __forceinline__ float4 b4_to_f4(ushort4 u) {
    return make_float4(b2f(u.x), b2f(u.y), b2f(u.z), b2f(u.w));
}

// ---------------------------------------------------------------------------
// K1h: history GEMV, async global_load_lds 3-deep x 1KB per-wave pipeline AT
// FULL OCCUPANCY (LDS 17.5KB -> (256,8) = 32 waves/CU, ~96KB/CU in flight).
// grid 2080, block 256 = 4 waves; wave w: rows k0+32w..+32, 256-col half.
// FMA order per lane identical to r19/r20 -> bit-identical ph.
// ph[16][64][512] f32
// ---------------------------------------------------------------------------
__global__ __launch_bounds__(256, 8) void k_hist(
        const float* __restrict__ pre, const float* __restrict__ W1,
        const float* __restrict__ emb, const float* __restrict__ Wp,
        const float* __restrict__ bp, float* __restrict__ proj,
        float* __restrict__ ph) {
    const int bid = blockIdx.x;
    const int t   = threadIdx.x;

    __shared__ float ps[128];
    __shared__ float red[4][256];
    __shared__ float wbuf[4][3][256];      // [wave][buf][col] = 12 KB

    if (bid >= 2048) {
        const int b = bid - 2048;
        __shared__ float e[MODEL_DIM];
        e[t] = emb[b * MODEL_DIM + t];
        __syncthreads();
        float acc = bp[t];
        #pragma unroll 4
        for (int k = 0; k < MODEL_DIM; ++k)
            acc = fmaf(e[k], Wp[(size_t)k * MODEL_DIM + t], acc);
        proj[b * MODEL_DIM + t] = acc;
        return;
    }

    const int n  = bid >> 5;
    const int ks = (bid >> 1) & 15;
    const int ch = bid & 1;
    const int w  = t >> 6;
    const int l  = t & 63;
    const int k0 = ks * 128;
    const int cb = ch * 256;

    if (t < 128) ps[t] = pre[k0 + t];
    __syncthreads();

    const float* Wb = W1 + (size_t)n * IN_DIM * HID
                         + (size_t)(MODEL_DIM + k0 + w * 32) * HID + cb;
    const float* gl = Wb + l * 4;          // per-lane global addr (16B/lane)
    const float* pw = ps + w * 32;
    float* b0 = &wbuf[w][0][0];            // wave-private buffers
    float* b1 = &wbuf[w][1][0];
    float* b2 = &wbuf[w][2][0];

    // prologue: issue rows 0..2 (3 outstanding)
    gll16(gl,                   b0);
    gll16(gl + (size_t)1 * HID, b1);
    gll16(gl + (size_t)2 * HID, b2);

    float4 a = make_float4(0.f, 0.f, 0.f, 0.f);
    #pragma unroll
    for (int bi = 0; bi < 32; ++bi) {
        float* cur = (bi % 3 == 0) ? b0 : ((bi % 3 == 1) ? b1 : b2);
        // wait until row bi has landed (later-issued rows may stay in flight)
        if (bi <= 29)      asm volatile("s_waitcnt vmcnt(2)" ::: "memory");
        else if (bi == 30) asm volatile("s_waitcnt vmcnt(1)" ::: "memory");
        else               asm volatile("s_waitcnt vmcnt(0)" ::: "memory");
        __builtin_amdgcn_sched_barrier(0);
        {
            float s = pw[bi];
            float4 wv = *((const float4*)(cur + l * 4));
            a.x = fmaf(s, wv.x, a.x);
            a.y = fmaf(s, wv.y, a.y);
            a.z = fmaf(s, wv.z, a.z);
            a.w = fmaf(s, wv.w, a.w);
        }
        if (bi + 3 < 32)
            gll16(gl + (size_t)(bi + 3) * HID, cur);   // refill just-consumed
    }

    *((float4*)&red[w][l * 4]) = a;
    __syncthreads();

    if (t < 64) {
        const int c = t * 4;
        float4 r0 = *((const float4*)&red[0][c]);
        float4 r1 = *((const float4*)&red[1][c]);
        float4 r2 = *((const float4*)&red[2][c]);
        float4 r3 = *((const float4*)&red[3][c]);
        float4 o = make_float4(r0.x + r1.x + r2.x + r3.x,
                               r0.y + r1.y + r2.y + r3.y,
                               r0.z + r1.z + r2.z + r3.z,
                               r0.w + r1.w + r2.w + r3.w);
        *((float4*)(ph + ((size_t)ks * NNEUR + n) * HID + cb + c)) = o;
    }
}

// ---------------------------------------------------------------------------
// K1p: proj GEMM + phs pre-reduction (r19/r20, unchanged).
// grid 512 = n(64) x ct(2) x ks(4: K=64). block 256. pp[4][64][32][512] bf16
// ---------------------------------------------------------------------------
__global__ __launch_bounds__(256, 4) void k_proj(
        const float* __restrict__ proj, const float* __restrict__ W1,
        const float* __restrict__ ph, float* __restrict__ phs,
        unsigned short* __restrict__ pp) {
    const int bid = blockIdx.x;
    const int t  = threadIdx.x;

    if (bid < 64) {
        const size_t slh = (size_t)NNEUR * HID;
        #pragma unroll
        for (int q = 0; q < 2; ++q) {
            const int c = t + q * 256;
            const float* h = ph + (size_t)bid * HID + c;
            float s = 0.0f;
            #pragma unroll
            for (int s5 = 0; s5 < 16; ++s5)
                s += h[(size_t)s5 * slh];
            phs[(size_t)bid * HID + c] = s;
        }
    }

    const int n  = bid >> 3;
    const int ct = (bid >> 2) & 1;
    const int ks = bid & 3;
    const int cg = t & 63;
    const int rg = t >> 6;
    const int col0 = ct * 256 + cg * 4;
    const int row0 = rg * 8;
    const int k0 = ks * 64;

    __shared__ float xs[BATCH][64];
    #pragma unroll
    for (int q = 0; q < 2; ++q) {                 // 32*16 float4 = 512
        int fi  = t + 256 * q;
        int row = fi >> 4;
        int c4v = fi & 15;
        *((float4*)&xs[row][c4v * 4]) =
            *((const float4*)(proj + (size_t)row * MODEL_DIM + k0 + c4v * 4));
    }
    __syncthreads();

    const float* W = W1 + (size_t)n * IN_DIM * HID + (size_t)k0 * HID + col0;

    float acc[8][4];
    #pragma unroll
    for (int i = 0; i < 8; ++i)
        #pragma unroll
        for (int j = 0; j < 4; ++j) acc[i][j] = 0.0f;

    for (int kg = 0; kg < 64; kg += 4) {
        float4 xv[8];
        #pragma unroll
        for (int i = 0; i < 8; ++i)
            xv[i] = *((const float4*)&xs[row0 + i][kg]);
        #pragma unroll
        for (int j = 0; j < 4; ++j) {
            float4 w = ntload4(W + (size_t)(kg + j) * HID);
            #pragma unroll
            for (int i = 0; i < 8; ++i) {
                float xvv = f4c(xv[i], j);
                acc[i][0] = fmaf(xvv, w.x, acc[i][0]);
                acc[i][1] = fmaf(xvv, w.y, acc[i][1]);
                acc[i][2] = fmaf(xvv, w.z, acc[i][2]);
                acc[i][3] = fmaf(xvv, w.w, acc[i][3]);
            }
        }
    }
    unsigned short* P = pp + (size_t)(ks * NNEUR + n) * BATCH * HID;
    #pragma unroll
    for (int i = 0; i < 8; ++i)
        *((ushort4*)(P + (size_t)(row0 + i) * HID + col0)) =
            f4_to_b4(make_float4(acc[i][0], acc[i][1], acc[i][2], acc[i][3]));
}

// ---------------------------------------------------------------------------
// K2: layer2 (r19/r20, unchanged). grid 1024 = n(64) x ct(2) x ks(8: K=64).
// block 256. p2[8][64][32][512] bf16
// ---------------------------------------------------------------------------
__global__ __launch_bounds__(256, 4) void k_layer2(
        const unsigned short* __restrict__ pp, const float* __restrict__ phs,
        const float* __restrict__ b1,
        const float* __restrict__ W2, unsigned short* __restrict__ p2) {
    const int bid = blockIdx.x;
    const int n  = bid >> 4;
    const int ct = (bid >> 3) & 1;
    const int ks = bid & 7;
    const int t  = threadIdx.x;
    const int cg = t & 63;
    const int rg = t >> 6;
    const int col0 = ct * 256 + cg * 4;
    const int row0 = rg * 8;
    const int k0 = ks * 64;

    const size_t slp = (size_t)NNEUR * BATCH * HID;   // pp slice stride

    __shared__ float xs[BATCH][64];
    #pragma unroll
    for (int q = 0; q < 2; ++q) {                 // 32*16 groups = 512
        int fi  = t + 256 * q;
        int row = fi >> 4;
        int c4v = fi & 15;
        const unsigned short* a = pp + ((size_t)n * BATCH + row) * HID + k0 + c4v * 4;
        float4 s0 = b4_to_f4(*((const ushort4*)(a)));
        float4 s1 = b4_to_f4(*((const ushort4*)(a + slp)));
        float4 s2 = b4_to_f4(*((const ushort4*)(a + 2 * slp)));
        float4 s3 = b4_to_f4(*((const ushort4*)(a + 3 * slp)));
        float4 hs = *((const float4*)(phs + (size_t)n * HID + k0 + c4v * 4));
        float4 bb = *((const float4*)(b1 + (size_t)n * HID + k0 + c4v * 4));
        *((float4*)&xs[row][c4v * 4]) = make_float4(
            geluf(s0.x + s1.x + s2.x + s3.x + hs.x + bb.x),
            geluf(s0.y + s1.y + s2.y + s3.y + hs.y + bb.y),
            geluf(s0.z + s1.z + s2.z + s3.z + hs.z + bb.z),
            geluf(s0.w + s1.w + s2.w + s3.w + hs.w + bb.w));
    }
    __syncthreads();

    const float* W = W2 + (size_t)n * HID * HID + (size_t)k0 * HID + col0;

    float acc[8][4];
    #pragma unroll
    for (int i = 0; i < 8; ++i)
        #pragma unroll
        for (int j = 0; j < 4; ++j) acc[i][j] = 0.0f;

    for (int kg = 0; kg < 64; kg += 4) {
        float4 xv[8];
        #pragma unroll
        for (int i = 0; i < 8; ++i)
            xv[i] = *((const float4*)&xs[row0 + i][kg]);
        #pragma unroll
        for (int j = 0; j < 4; ++j) {
            float4 w = ntload4(W + (size_t)(kg + j) * HID);
            #pragma unroll
            for (int i = 0; i < 8; ++i) {
                float xvv = f4c(xv[i], j);
                acc[i][0] = fmaf(xvv, w.x, acc[i][0]);
                acc[i][1] = fmaf(xvv, w.y, acc[i][1]);
                acc[i][2] = fmaf(xvv, w.z, acc[i][2]);
                acc[i][3] = fmaf(xvv, w.w, acc[i][3]);
            }
        }
    }
    unsigned short* P = p2 + (size_t)(ks * NNEUR + n) * BATCH * HID;
    #pragma unroll
    for (int i = 0; i < 8; ++i)
        *((ushort4*)(P + (size_t)(row0 + i) * HID + col0)) =
            f4_to_b4(make_float4(acc[i][0], acc[i][1], acc[i][2], acc[i][3]));
}

// ---------------------------------------------------------------------------
// K3: layer3 (r19/r20, unchanged). grid 1024 = n(64) x ks(16: K=32).
// block 256. p3[16][64][32][256] bf16
// ---------------------------------------------------------------------------
__global__ __launch_bounds__(256, 4) void k_layer3(
        const unsigned short* __restrict__ p2, const float* __restrict__ b2,
        const float* __restrict__ W3, unsigned short* __restrict__ p3) {
    const int bid = blockIdx.x;
    const int n  = bid >> 4;
    const int ks = bid & 15;
    const int t  = threadIdx.x;
    const int cg = t & 63;
    const int rg = t >> 6;
    const int col0 = cg * 4;
    const int row0 = rg * 8;
    const int k0 = ks * 32;

    const size_t sl = (size_t)NNEUR * BATCH * HID;

    __shared__ float xs[BATCH][32];
    {                                             // 32*8 groups = 256
        int row = t >> 3;
        int c4v = t & 7;
        const unsigned short* a = p2 + ((size_t)n * BATCH + row) * HID + k0 + c4v * 4;
        float4 s0 = b4_to_f4(*((const ushort4*)(a)));
        float4 s1 = b4_to_f4(*((const ushort4*)(a + sl)));
        float4 s2 = b4_to_f4(*((const ushort4*)(a + 2 * sl)));
        float4 s3 = b4_to_f4(*((const ushort4*)(a + 3 * sl)));
        float4 s4 = b4_to_f4(*((const ushort4*)(a + 4 * sl)));
        float4 s5 = b4_to_f4(*((const ushort4*)(a + 5 * sl)));
        float4 s6 = b4_to_f4(*((const ushort4*)(a + 6 * sl)));
        float4 s7 = b4_to_f4(*((const ushort4*)(a + 7 * sl)));
        float4 bb = *((const float4*)(b2 + (size_t)n * HID + k0 + c4v * 4));
        *((float4*)&xs[row][c4v * 4]) = make_float4(
            geluf(s0.x+s1.x+s2.x+s3.x+s4.x+s5.x+s6.x+s7.x + bb.x),
            geluf(s0.y+s1.y+s2.y+s3.y+s4.y+s5.y+s6.y+s7.y + bb.y),
            geluf(s0.z+s1.z+s2.z+s3.z+s4.z+s5.z+s6.z+s7.z + bb.z),
            geluf(s0.w+s1.w+s2.w+s3.w+s4.w+s5.w+s6.w+s7.w + bb.w));
    }
    __syncthreads();

    const float* W = W3 + (size_t)n * HID * MODEL_DIM + (size_t)k0 * MODEL_DIM + col0;

    float acc[8][4];
    #pragma unroll
    for (int i = 0; i < 8; ++i)
        #pragma unroll
        for (int j = 0; j < 4; ++j) acc[i][j] = 0.0f;

    for (int kg = 0; kg < 32; kg += 4) {
        float4 xv[8];
        #pragma unroll
        for (int i = 0; i < 8; ++i)
            xv[i] = *((const float4*)&xs[row0 + i][kg]);
        #pragma unroll
        for (int j = 0; j < 4; ++j) {
            float4 w = ntload4(W + (size_t)(kg + j) * MODEL_DIM);
            #pragma unroll
            for (int i = 0; i < 8; ++i) {
                float xvv = f4c(xv[i], j);
                acc[i][0] = fmaf(xvv, w.x, acc[i][0]);
                acc[i][1] = fmaf(xvv, w.y, acc[i][1]);
                acc[i][2] = fmaf(xvv, w.z, acc[i][2]);
                acc[i][3] = fmaf(xvv, w.w, acc[i][3]);
            }
        }
    }
    unsigned short* P = p3 + (size_t)(ks * NNEUR + n) * BATCH * MODEL_DIM;
    #pragma unroll
    for (int i = 0; i < 8; ++i)
        *((ushort4*)(P + (size_t)(row0 + i) * MODEL_DIM + col0)) =
            f4_to_b4(make_float4(acc[i][0], acc[i][1], acc[i][2], acc[i][3]));
}

// ---------------------------------------------------------------------------
// K4: y = sum(p3[0..15] bf16) + b3 ; LayerNorm ; oscillator mod ; f32 store
// ---------------------------------------------------------------------------
__global__ __launch_bounds__(256) void k_final(
        const unsigned short* __restrict__ p3, const float* __restrict__ b3,
        const float* __restrict__ gamma, const float* __restrict__ beta,
        const int* __restrict__ tick, float* __restrict__ out) {
    const int n  = blockIdx.x >> 3;
    const int bq = blockIdx.x & 7;
    const int t  = threadIdx.x;
    const int w  = t >> 6;
    const int lane = t & 63;
    const int b  = bq * 4 + w;

    const size_t par0 = (size_t)n * MODEL_DIM;
    const size_t rowoff = ((size_t)n * BATCH + b) * MODEL_DIM;
    const size_t sl = (size_t)NNEUR * BATCH * MODEL_DIM;

    float y[4];
    #pragma unroll
    for (int j = 0; j < 4; ++j) {
        int d = lane + 64 * j;
        float v = b3[par0 + d];
        #pragma unroll
        for (int s = 0; s < 16; ++s)
            v += b2f(p3[s * sl + rowoff + d]);
        y[j] = v;
    }
    float s = y[0] + y[1] + y[2] + y[3];
    #pragma unroll
    for (int off = 32; off > 0; off >>= 1) s += __shfl_xor(s, off);
    float mu = s * (1.0f / 256.0f);
    float q = 0.0f;
    #pragma unroll
    for (int j = 0; j < 4; ++j) { float d0 = y[j] - mu; q = fmaf(d0, d0, q); }
    #pragma unroll
    for (int off = 32; off > 0; off >>= 1) q += __shfl_xor(q, off);
    float inv = rsqrtf(q * (1.0f / 256.0f) + 1e-5f);

    const double TWO_PI = 6.283185307179586476925287;
    double freq  = 0.5 * pow(80.0, (double)n * (1.0 / 63.0));
    double phase = fmod((double)n * 2.3571, TWO_PI);
    double tt    = (double)(*tick) * 0.1;
    float mod = (float)(1.0 + 0.5 * sin(TWO_PI * freq * tt + phase));

    #pragma unroll
    for (int j = 0; j < 4; ++j) {
        int d = lane + 64 * j;
        float o = (y[j] - mu) * inv * gamma[par0 + d] + beta[par0 + d];
        o *= mod;
        out[((size_t)b * NNEUR + n) * MODEL_DIM + d] = o;
    }
}

// ---------------------------------------------------------------------------
extern "C" void kernel_launch(void* const* d_in, const int* in_sizes, int n_in,
                              void* d_out, int out_size, void* d_ws, size_t ws_size,
                              hipStream_t stream) {
    const float* emb  = (const float*)d_in[0];
    const float* pre  = (const float*)d_in[1];
    const float* Wp   = (const float*)d_in[2];
    const float* bp   = (const float*)d_in[3];
    const float* W1   = (const float*)d_in[4];
    const float* b1   = (const float*)d_in[5];
    const float* W2   = (const float*)d_in[6];
    const float* b2   = (const float*)d_in[7];
    const float* W3   = (const float*)d_in[8];
    const float* b3   = (const float*)d_in[9];
    const float* gam  = (const float*)d_in[10];
    const float* bet  = (const float*)d_in[11];
    const int* tick   = (const int*)d_in[12];

    float* ws = (float*)d_ws;
    float* proj = ws;                            // 32*256            =    8192 f32
    float* ph  = proj + 8192;                    // [16][64][512]     =  524288 f32
    float* phs = ph + 524288;                    // [64][512]         =   32768 f32
    unsigned short* pp = (unsigned short*)(phs + 32768);  // [4][64][32][512]  bf16 (8MB)
    unsigned short* p2 = pp + 4194304;           // [8][64][32][512]  bf16 (16MB)
    unsigned short* p3 = p2 + 8388608;           // [16][64][32][256] bf16 (16MB)
    float* out = (float*)d_out;

    k_hist   <<<2080, 256, 0, stream>>>(pre, W1, emb, Wp, bp, proj, ph);
    k_proj   <<<512,  256, 0, stream>>>(proj, W1, ph, phs, pp);
    k_layer2 <<<1024, 256, 0, stream>>>(pp, phs, b1, W2, p2);
    k_layer3 <<<1024, 256, 0, stream>>>(p2, b2, W3, p3);
    k_final  <<<512,  256, 0, stream>>>(p3, b3, gam, bet, tick, out);
}